// Round 5
// baseline (250.664 us; speedup 1.0000x reference)
//
#include <hip/hip_runtime.h>
#include <hip/hip_bf16.h>

// Ensemble MLP: E=8, B=16384, DS=32, DA=8, H=128, din=40 (padded to 64 for K).
// preds[i,j,b,:] = MLP_j(inp[i,b,:]); out0 = mean_i(preds)+states, out1 = var_i(preds, ddof=1)
//
// R5 = R4 + operand flip: weights are the A operand, activations are the B
// operand (per-lane frag layouts are identical: [out-idx=lane&15][k=q*8+t], so
// the weight registers are reused unchanged). C comes out transposed -> each
// lane holds 4 CONSECUTIVE FEATURES of one batch row: hidden stores become
// packed ds_write_b64 (was 4x ds_write_b16 w/ 4-way conflicts), conversion is
// packed bf16x2, epilogue is float4. b2 bias deferred algebraically:
// sum(a+b)^2 = sq + 2b*sa + 8b^2. R4 diagnosis: VALU-bound (49%) on hidden
// epilogues, MFMA only 18.7%.

#define NE 8
#define NB 16384
#define DS 32
#define DA 8
#define HH 128
#define DIN 40
#define BT 64            // batch rows per block
#define SIN_STRIDE 72    // 64 + 8 pad (bf16 elements)
#define SH_STRIDE 136    // 128 + 8 pad
#define SLOPE 0.01f

using bf16x8 = __attribute__((ext_vector_type(8))) short;
using f32x4  = __attribute__((ext_vector_type(4))) float;

__device__ __forceinline__ unsigned short f2bf(float f) {
    unsigned int u = __float_as_uint(f);
    u += 0x7FFFu + ((u >> 16) & 1u);
    return (unsigned short)(u >> 16);
}

__device__ __forceinline__ float lrelu(float x) { return fmaxf(x, SLOPE * x); }

__device__ __forceinline__ unsigned int pack2bf(float a, float b) {
    union { __hip_bfloat162 h; unsigned int u; } cv;
    cv.h = __float22bfloat162_rn(make_float2(a, b));   // a -> low 16, b -> high 16
    return cv.u;
}

__global__ __launch_bounds__(256, 3)
void ens_mlp_kernel(const float* __restrict__ states,
                    const float* __restrict__ actions,
                    const float* __restrict__ W0g,
                    const float* __restrict__ b0g,
                    const float* __restrict__ W1g,
                    const float* __restrict__ b1g,
                    const float* __restrict__ W2g,
                    const float* __restrict__ b2g,
                    float* __restrict__ out)
{
    __shared__ __align__(16) unsigned short sIn[BT * SIN_STRIDE];
    __shared__ __align__(16) unsigned short sHa[BT * SH_STRIDE];
    __shared__ __align__(16) unsigned short sHb[BT * SH_STRIDE];

    const int j    = blockIdx.x & 7;          // j fast-varying
    const int bt   = blockIdx.x >> 3;
    const int b0   = bt * BT;
    const int tid  = threadIdx.x;
    const int wave = tid >> 6;
    const int lane = tid & 63;
    const int q    = lane >> 4;
    const int l16  = lane & 15;
    const int fb   = 32 * wave;               // L0/L1: wave owns features fb..fb+31 (M dim)

    // zero sIn FIRST (cols 40..63 stay zero = K padding); weight prologue sits
    // between this and the barrier before staging (R4 race fix preserved).
    for (int idx = tid; idx < BT * SIN_STRIDE; idx += 256) sIn[idx] = 0;

    const float* W0j = W0g + j * (DIN * HH);
    const float* W1j = W1g + j * (HH * HH);
    const float* W2j = W2g + j * (HH * DS);

    // ---- Weight A-fragments: lane holds W[k = ks*32 + q*8 + t][feature = base + l16]
    bf16x8 w0f[2][2];   // [ks][mt], feature = fb + mt*16 + l16   (16 VGPRs)
    bf16x8 w1f[4][2];   // 32 VGPRs
    bf16x8 w2f[4][2];   // [ks][mt], feature = mt*16 + l16 (full W2 per wave, 32 VGPRs)
    float b0r[2][4], b1r[2][4], b2r[2][4];

    #pragma unroll
    for (int ks = 0; ks < 2; ++ks)
      #pragma unroll
      for (int mt = 0; mt < 2; ++mt) {
        const int n = fb + mt * 16 + l16;
        #pragma unroll
        for (int t = 0; t < 8; ++t) {
          const int k = ks * 32 + q * 8 + t;
          const float v = (k < DIN) ? W0j[k * HH + n] : 0.f;
          w0f[ks][mt][t] = (short)f2bf(v);
        }
      }
    #pragma unroll
    for (int ks = 0; ks < 4; ++ks)
      #pragma unroll
      for (int mt = 0; mt < 2; ++mt) {
        const int n = fb + mt * 16 + l16;
        #pragma unroll
        for (int t = 0; t < 8; ++t) {
          const int k = ks * 32 + q * 8 + t;
          w1f[ks][mt][t] = (short)f2bf(W1j[k * HH + n]);
        }
      }
    #pragma unroll
    for (int ks = 0; ks < 4; ++ks)
      #pragma unroll
      for (int mt = 0; mt < 2; ++mt) {
        const int n = mt * 16 + l16;
        #pragma unroll
        for (int t = 0; t < 8; ++t) {
          const int k = ks * 32 + q * 8 + t;
          w2f[ks][mt][t] = (short)f2bf(W2j[k * DS + n]);
        }
      }
    #pragma unroll
    for (int mt = 0; mt < 2; ++mt)
      #pragma unroll
      for (int r = 0; r < 4; ++r) {
        b0r[mt][r] = b0g[j * HH + fb + mt * 16 + q * 4 + r];
        b1r[mt][r] = b1g[j * HH + fb + mt * 16 + q * 4 + r];
        b2r[mt][r] = b2g[j * DS + mt * 16 + q * 4 + r];
      }

    float sa[2][4], sq[2][4];
    #pragma unroll
    for (int mt = 0; mt < 2; ++mt)
      #pragma unroll
      for (int r = 0; r < 4; ++r) { sa[mt][r] = 0.f; sq[mt][r] = 0.f; }

    const f32x4 z4 = {0.f, 0.f, 0.f, 0.f};

    __syncthreads();   // zero-writes drained before staging scatters

    // ---- stage inp[0] ----
    {
        const float* stp = states  + ((size_t)0 * NB + b0) * DS;
        for (int idx = tid; idx < BT * DS; idx += 256) {
            const int r = idx >> 5, c = idx & 31;
            sIn[r * SIN_STRIDE + c] = f2bf(stp[r * DS + c]);
        }
        const float* atp = actions + ((size_t)0 * NB + b0) * DA;
        for (int idx = tid; idx < BT * DA; idx += 256) {
            const int r = idx >> 3, c = idx & 7;
            sIn[r * SIN_STRIDE + DS + c] = f2bf(atp[r * DA + c]);
        }
    }
    __syncthreads();

    for (int i = 0; i < NE; ++i) {
        // ---- Layer 0: h0[b][f] = lrelu(inp @ W0 + b0); C: m=feature, n=batch ----
        #pragma unroll
        for (int nh = 0; nh < 2; ++nh) {          // batch halves (acc cap = 16)
            f32x4 acc[2][2];
            #pragma unroll
            for (int mt = 0; mt < 2; ++mt)
              #pragma unroll
              for (int nt = 0; nt < 2; ++nt) acc[mt][nt] = z4;
            #pragma unroll
            for (int ks = 0; ks < 2; ++ks) {
                bf16x8 bf[2];
                #pragma unroll
                for (int nt = 0; nt < 2; ++nt) {
                    const int row = nh * 32 + nt * 16 + l16;   // B: n = lane&15
                    bf[nt] = *(const bf16x8*)(&sIn[row * SIN_STRIDE + ks * 32 + q * 8]);
                }
                #pragma unroll
                for (int mt = 0; mt < 2; ++mt)
                  #pragma unroll
                  for (int nt = 0; nt < 2; ++nt)
                    acc[mt][nt] = __builtin_amdgcn_mfma_f32_16x16x32_bf16(
                        w0f[ks][mt], bf[nt], acc[mt][nt], 0, 0, 0);
            }
            // lane holds 4 consecutive features (q*4+r) of batch row nt*16+l16
            #pragma unroll
            for (int mt = 0; mt < 2; ++mt)
              #pragma unroll
              for (int nt = 0; nt < 2; ++nt) {
                const int row  = nh * 32 + nt * 16 + l16;
                const int base = row * SH_STRIDE + fb + mt * 16 + q * 4;
                const float v0 = lrelu(acc[mt][nt][0] + b0r[mt][0]);
                const float v1 = lrelu(acc[mt][nt][1] + b0r[mt][1]);
                const float v2 = lrelu(acc[mt][nt][2] + b0r[mt][2]);
                const float v3 = lrelu(acc[mt][nt][3] + b0r[mt][3]);
                uint2 pk; pk.x = pack2bf(v0, v1); pk.y = pack2bf(v2, v3);
                *reinterpret_cast<uint2*>(&sHa[base]) = pk;
              }
        }
        __syncthreads();   // B2: h0 ready; sIn reads drained (safe to restage)

        // ---- stage inp[i+1] (overlaps L1) ----
        if (i < NE - 1) {
            const float* stp = states  + ((size_t)(i + 1) * NB + b0) * DS;
            for (int idx = tid; idx < BT * DS; idx += 256) {
                const int r = idx >> 5, c = idx & 31;
                sIn[r * SIN_STRIDE + c] = f2bf(stp[r * DS + c]);
            }
            const float* atp = actions + ((size_t)(i + 1) * NB + b0) * DA;
            for (int idx = tid; idx < BT * DA; idx += 256) {
                const int r = idx >> 3, c = idx & 7;
                sIn[r * SIN_STRIDE + DS + c] = f2bf(atp[r * DA + c]);
            }
        }

        // ---- Layer 1: h1 = lrelu(h0 @ W1 + b1), K=128; reads sHa, writes sHb ----
        #pragma unroll
        for (int nh = 0; nh < 2; ++nh) {
            f32x4 acc[2][2];
            #pragma unroll
            for (int mt = 0; mt < 2; ++mt)
              #pragma unroll
              for (int nt = 0; nt < 2; ++nt) acc[mt][nt] = z4;
            #pragma unroll
            for (int ks = 0; ks < 4; ++ks) {
                bf16x8 bf[2];
                #pragma unroll
                for (int nt = 0; nt < 2; ++nt) {
                    const int row = nh * 32 + nt * 16 + l16;
                    bf[nt] = *(const bf16x8*)(&sHa[row * SH_STRIDE + ks * 32 + q * 8]);
                }
                #pragma unroll
                for (int mt = 0; mt < 2; ++mt)
                  #pragma unroll
                  for (int nt = 0; nt < 2; ++nt)
                    acc[mt][nt] = __builtin_amdgcn_mfma_f32_16x16x32_bf16(
                        w1f[ks][mt], bf[nt], acc[mt][nt], 0, 0, 0);
            }
            #pragma unroll
            for (int mt = 0; mt < 2; ++mt)
              #pragma unroll
              for (int nt = 0; nt < 2; ++nt) {
                const int row  = nh * 32 + nt * 16 + l16;
                const int base = row * SH_STRIDE + fb + mt * 16 + q * 4;
                const float v0 = lrelu(acc[mt][nt][0] + b1r[mt][0]);
                const float v1 = lrelu(acc[mt][nt][1] + b1r[mt][1]);
                const float v2 = lrelu(acc[mt][nt][2] + b1r[mt][2]);
                const float v3 = lrelu(acc[mt][nt][3] + b1r[mt][3]);
                uint2 pk; pk.x = pack2bf(v0, v1); pk.y = pack2bf(v2, v3);
                *reinterpret_cast<uint2*>(&sHb[base]) = pk;
              }
        }
        __syncthreads();   // B3: h1 + sIn(i+1) ready

        // ---- Layer 2: acc += h1 @ W2 (b2 deferred); wave owns 16 batch rows ----
        {
            f32x4 acc2[2];
            acc2[0] = z4; acc2[1] = z4;
            const int row = 16 * wave + l16;
            #pragma unroll
            for (int ks = 0; ks < 4; ++ks) {
                const bf16x8 bf = *(const bf16x8*)(&sHb[row * SH_STRIDE + ks * 32 + q * 8]);
                #pragma unroll
                for (int mt = 0; mt < 2; ++mt)
                    acc2[mt] = __builtin_amdgcn_mfma_f32_16x16x32_bf16(
                        w2f[ks][mt], bf, acc2[mt], 0, 0, 0);
            }
            #pragma unroll
            for (int mt = 0; mt < 2; ++mt)
              #pragma unroll
              for (int r = 0; r < 4; ++r) {
                const float a = acc2[mt][r];
                sa[mt][r] += a;
                sq[mt][r] = fmaf(a, a, sq[mt][r]);
              }
        }
    }

    // ---- Epilogue: p_i = a_i + b2. sum = sa + 8b; sum(p^2) = sq + 2b*sa + 8b^2 ----
    {
        const int n = 16 * wave + l16;            // batch row
        #pragma unroll
        for (int mt = 0; mt < 2; ++mt) {
            const size_t o = ((size_t)j * NB + b0 + n) * DS + mt * 16 + q * 4;
            const f32x4 st = *(const f32x4*)(states + o);
            f32x4 mean4, var4;
            #pragma unroll
            for (int r = 0; r < 4; ++r) {
                const float b  = b2r[mt][r];
                const float s  = sa[mt][r] + 8.f * b;
                const float s2 = sq[mt][r] + 2.f * b * sa[mt][r] + 8.f * b * b;
                mean4[r] = s * 0.125f + st[r];
                var4[r]  = (s2 - s * s * 0.125f) * (1.0f / 7.0f);
            }
            *(f32x4*)(out + o) = mean4;
            *(f32x4*)(out + (size_t)NE * NB * DS + o) = var4;
        }
    }
}

extern "C" void kernel_launch(void* const* d_in, const int* in_sizes, int n_in,
                              void* d_out, int out_size, void* d_ws, size_t ws_size,
                              hipStream_t stream) {
    (void)in_sizes; (void)n_in; (void)d_ws; (void)ws_size; (void)out_size;
    const float* states  = (const float*)d_in[0];
    const float* actions = (const float*)d_in[1];
    const float* W0 = (const float*)d_in[2];
    const float* b0 = (const float*)d_in[3];
    const float* W1 = (const float*)d_in[4];
    const float* b1 = (const float*)d_in[5];
    const float* W2 = (const float*)d_in[6];
    const float* b2 = (const float*)d_in[7];
    float* out = (float*)d_out;
    dim3 grid(NE * (NB / BT));   // 2048 blocks
    ens_mlp_kernel<<<grid, dim3(256), 0, stream>>>(states, actions, W0, b0, W1, b1, W2, b2, out);
}

// Round 6
// 184.192 us; speedup vs baseline: 1.3609x; 1.3609x over previous
//
#include <hip/hip_runtime.h>
#include <hip/hip_bf16.h>

// Ensemble MLP: E=8, B=16384, DS=32, DA=8, H=128, din=40 (padded to 64 for K).
// preds[i,j,b,:] = MLP_j(inp[i,b,:]); out0 = mean_i(preds)+states, out1 = var_i(preds, ddof=1)
//
// R6 = R5 spill fix. R5's +40 persistent regs (w2f 32, biases 24) crossed the
// (256,3) budget (~170) -> scratch spill in the i-loop (+214 MB HBM traffic).
// Changes: (1) L2 reverts to R4 orientation (weights as B): w2f 16 regs, b2r
// scalar. (2) b0 folded into MFMA via K-padding: W0 row 40 = b0, sIn col 40 =
// 1.0 (constant across i; staging only writes cols 0..39). (3) keep L0/L1
// weights-as-A flip: packed ds_write_b64 hidden stores + bf16x2 packing.
// Persistent regs ~89, loop-live ~50 -> ~140 < 170, spill-free.

#define NE 8
#define NB 16384
#define DS 32
#define DA 8
#define HH 128
#define DIN 40
#define BT 64            // batch rows per block
#define SIN_STRIDE 72    // 64 + 8 pad (bf16 elements)
#define SH_STRIDE 136    // 128 + 8 pad
#define SLOPE 0.01f

using bf16x8 = __attribute__((ext_vector_type(8))) short;
using f32x4  = __attribute__((ext_vector_type(4))) float;

__device__ __forceinline__ unsigned short f2bf(float f) {
    unsigned int u = __float_as_uint(f);
    u += 0x7FFFu + ((u >> 16) & 1u);
    return (unsigned short)(u >> 16);
}

__device__ __forceinline__ float lrelu(float x) { return fmaxf(x, SLOPE * x); }

__device__ __forceinline__ unsigned int pack2bf(float a, float b) {
    union { __hip_bfloat162 h; unsigned int u; } cv;
    cv.h = __float22bfloat162_rn(make_float2(a, b));   // a -> low 16, b -> high 16
    return cv.u;
}

__global__ __launch_bounds__(256, 3)
void ens_mlp_kernel(const float* __restrict__ states,
                    const float* __restrict__ actions,
                    const float* __restrict__ W0g,
                    const float* __restrict__ b0g,
                    const float* __restrict__ W1g,
                    const float* __restrict__ b1g,
                    const float* __restrict__ W2g,
                    const float* __restrict__ b2g,
                    float* __restrict__ out)
{
    __shared__ __align__(16) unsigned short sIn[BT * SIN_STRIDE];
    __shared__ __align__(16) unsigned short sHa[BT * SH_STRIDE];
    __shared__ __align__(16) unsigned short sHb[BT * SH_STRIDE];

    const int j    = blockIdx.x & 7;          // j fast-varying
    const int bt   = blockIdx.x >> 3;
    const int b0   = bt * BT;
    const int tid  = threadIdx.x;
    const int wave = tid >> 6;
    const int lane = tid & 63;
    const int q    = lane >> 4;
    const int l16  = lane & 15;
    const int fb   = 32 * wave;               // L0/L1: wave owns features fb..fb+31 (A/M dim)
    const int l2m  = 32 * (wave >> 1);        // L2 (R4 orientation): rows l2m..l2m+31
    const int l2n  = 16 * (wave & 1);         //                      cols l2n..l2n+15

    // zero sIn FIRST (cols 41..63 stay zero = K padding); weight prologue sits
    // between this and the barrier before staging (R4 race fix preserved).
    for (int idx = tid; idx < BT * SIN_STRIDE; idx += 256) sIn[idx] = 0;

    const float* W0j = W0g + j * (DIN * HH);
    const float* W1j = W1g + j * (HH * HH);
    const float* W2j = W2g + j * (HH * DS);

    // ---- L0/L1 weight A-fragments: lane holds W[k = ks*32+q*8+t][feat = base+l16]
    bf16x8 w0f[2][2];   // 16 VGPRs; row 40 carries b0 (bias-via-MFMA)
    bf16x8 w1f[4][2];   // 32 VGPRs
    // ---- L2 weight B-fragment (R4 orientation): B[k][n = l2n+l16]
    bf16x8 w2f[4];      // 16 VGPRs
    float b1r[2][4];
    float b2s;

    #pragma unroll
    for (int ks = 0; ks < 2; ++ks)
      #pragma unroll
      for (int mt = 0; mt < 2; ++mt) {
        const int n = fb + mt * 16 + l16;
        #pragma unroll
        for (int t = 0; t < 8; ++t) {
          const int k = ks * 32 + q * 8 + t;
          const float v = (k < DIN) ? W0j[k * HH + n]
                        : (k == DIN ? b0g[j * HH + n] : 0.f);
          w0f[ks][mt][t] = (short)f2bf(v);
        }
      }
    #pragma unroll
    for (int ks = 0; ks < 4; ++ks)
      #pragma unroll
      for (int mt = 0; mt < 2; ++mt) {
        const int n = fb + mt * 16 + l16;
        #pragma unroll
        for (int t = 0; t < 8; ++t) {
          const int k = ks * 32 + q * 8 + t;
          w1f[ks][mt][t] = (short)f2bf(W1j[k * HH + n]);
        }
      }
    #pragma unroll
    for (int ks = 0; ks < 4; ++ks) {
        const int n = l2n + l16;
        #pragma unroll
        for (int t = 0; t < 8; ++t) {
          const int k = ks * 32 + q * 8 + t;
          w2f[ks][t] = (short)f2bf(W2j[k * DS + n]);
        }
    }
    #pragma unroll
    for (int mt = 0; mt < 2; ++mt)
      #pragma unroll
      for (int r = 0; r < 4; ++r)
        b1r[mt][r] = b1g[j * HH + fb + mt * 16 + q * 4 + r];
    b2s = b2g[j * DS + l2n + l16];

    float sa[2][4], sq[2][4];
    #pragma unroll
    for (int mt = 0; mt < 2; ++mt)
      #pragma unroll
      for (int r = 0; r < 4; ++r) { sa[mt][r] = 0.f; sq[mt][r] = 0.f; }

    const f32x4 z4 = {0.f, 0.f, 0.f, 0.f};

    __syncthreads();   // zero-writes drained before any sIn rewrites

    // ones column for bias-via-MFMA (col 40; staging never touches it -> no race,
    // and it persists across all i)
    if (tid < BT) sIn[tid * SIN_STRIDE + DIN] = 0x3F80;  // bf16 1.0

    // ---- stage inp[0] ----
    {
        const float* stp = states  + ((size_t)0 * NB + b0) * DS;
        for (int idx = tid; idx < BT * DS; idx += 256) {
            const int r = idx >> 5, c = idx & 31;
            sIn[r * SIN_STRIDE + c] = f2bf(stp[r * DS + c]);
        }
        const float* atp = actions + ((size_t)0 * NB + b0) * DA;
        for (int idx = tid; idx < BT * DA; idx += 256) {
            const int r = idx >> 3, c = idx & 7;
            sIn[r * SIN_STRIDE + DS + c] = f2bf(atp[r * DA + c]);
        }
    }
    __syncthreads();

    for (int i = 0; i < NE; ++i) {
        // ---- Layer 0: h0 = lrelu(inp @ W0 + b0); A=W0 (m=feature), B=inp (n=batch)
        #pragma unroll
        for (int nh = 0; nh < 2; ++nh) {          // batch halves
            f32x4 acc[2][2];
            #pragma unroll
            for (int mt = 0; mt < 2; ++mt)
              #pragma unroll
              for (int nt = 0; nt < 2; ++nt) acc[mt][nt] = z4;
            #pragma unroll
            for (int ks = 0; ks < 2; ++ks) {
                bf16x8 bf[2];
                #pragma unroll
                for (int nt = 0; nt < 2; ++nt) {
                    const int row = nh * 32 + nt * 16 + l16;   // B: n = lane&15
                    bf[nt] = *(const bf16x8*)(&sIn[row * SIN_STRIDE + ks * 32 + q * 8]);
                }
                #pragma unroll
                for (int mt = 0; mt < 2; ++mt)
                  #pragma unroll
                  for (int nt = 0; nt < 2; ++nt)
                    acc[mt][nt] = __builtin_amdgcn_mfma_f32_16x16x32_bf16(
                        w0f[ks][mt], bf[nt], acc[mt][nt], 0, 0, 0);
            }
            // lane holds 4 consecutive features (q*4+r) of batch row nt*16+l16
            #pragma unroll
            for (int mt = 0; mt < 2; ++mt)
              #pragma unroll
              for (int nt = 0; nt < 2; ++nt) {
                const int row  = nh * 32 + nt * 16 + l16;
                const int base = row * SH_STRIDE + fb + mt * 16 + q * 4;
                const float v0 = lrelu(acc[mt][nt][0]);   // b0 already in acc
                const float v1 = lrelu(acc[mt][nt][1]);
                const float v2 = lrelu(acc[mt][nt][2]);
                const float v3 = lrelu(acc[mt][nt][3]);
                uint2 pk; pk.x = pack2bf(v0, v1); pk.y = pack2bf(v2, v3);
                *reinterpret_cast<uint2*>(&sHa[base]) = pk;
              }
        }
        __syncthreads();   // B2: h0 ready; sIn reads drained (safe to restage)

        // ---- stage inp[i+1] (overlaps L1; cols 0..39 only, col 40 stays 1.0) ----
        if (i < NE - 1) {
            const float* stp = states  + ((size_t)(i + 1) * NB + b0) * DS;
            for (int idx = tid; idx < BT * DS; idx += 256) {
                const int r = idx >> 5, c = idx & 31;
                sIn[r * SIN_STRIDE + c] = f2bf(stp[r * DS + c]);
            }
            const float* atp = actions + ((size_t)(i + 1) * NB + b0) * DA;
            for (int idx = tid; idx < BT * DA; idx += 256) {
                const int r = idx >> 3, c = idx & 7;
                sIn[r * SIN_STRIDE + DS + c] = f2bf(atp[r * DA + c]);
            }
        }

        // ---- Layer 1: h1 = lrelu(h0 @ W1 + b1), K=128; reads sHa, writes sHb ----
        #pragma unroll
        for (int nh = 0; nh < 2; ++nh) {
            f32x4 acc[2][2];
            #pragma unroll
            for (int mt = 0; mt < 2; ++mt)
              #pragma unroll
              for (int nt = 0; nt < 2; ++nt) acc[mt][nt] = z4;
            #pragma unroll
            for (int ks = 0; ks < 4; ++ks) {
                bf16x8 bf[2];
                #pragma unroll
                for (int nt = 0; nt < 2; ++nt) {
                    const int row = nh * 32 + nt * 16 + l16;
                    bf[nt] = *(const bf16x8*)(&sHa[row * SH_STRIDE + ks * 32 + q * 8]);
                }
                #pragma unroll
                for (int mt = 0; mt < 2; ++mt)
                  #pragma unroll
                  for (int nt = 0; nt < 2; ++nt)
                    acc[mt][nt] = __builtin_amdgcn_mfma_f32_16x16x32_bf16(
                        w1f[ks][mt], bf[nt], acc[mt][nt], 0, 0, 0);
            }
            #pragma unroll
            for (int mt = 0; mt < 2; ++mt)
              #pragma unroll
              for (int nt = 0; nt < 2; ++nt) {
                const int row  = nh * 32 + nt * 16 + l16;
                const int base = row * SH_STRIDE + fb + mt * 16 + q * 4;
                const float v0 = lrelu(acc[mt][nt][0] + b1r[mt][0]);
                const float v1 = lrelu(acc[mt][nt][1] + b1r[mt][1]);
                const float v2 = lrelu(acc[mt][nt][2] + b1r[mt][2]);
                const float v3 = lrelu(acc[mt][nt][3] + b1r[mt][3]);
                uint2 pk; pk.x = pack2bf(v0, v1); pk.y = pack2bf(v2, v3);
                *reinterpret_cast<uint2*>(&sHb[base]) = pk;
              }
        }
        __syncthreads();   // B3: h1 + sIn(i+1) ready

        // ---- Layer 2 (R4 orientation): A=h1 (m=batch), B=W2 (n=feature) ----
        {
            f32x4 acc2[2];
            acc2[0] = z4; acc2[1] = z4;
            #pragma unroll
            for (int ks = 0; ks < 4; ++ks) {
                #pragma unroll
                for (int mt = 0; mt < 2; ++mt) {
                    const int row = l2m + 16 * mt + l16;
                    const bf16x8 a2 = *(const bf16x8*)(&sHb[row * SH_STRIDE + ks * 32 + q * 8]);
                    acc2[mt] = __builtin_amdgcn_mfma_f32_16x16x32_bf16(
                        a2, w2f[ks], acc2[mt], 0, 0, 0);
                }
            }
            #pragma unroll
            for (int mt = 0; mt < 2; ++mt)
              #pragma unroll
              for (int r = 0; r < 4; ++r) {
                const float a = acc2[mt][r];      // b2 deferred
                sa[mt][r] += a;
                sq[mt][r] = fmaf(a, a, sq[mt][r]);
              }
        }
    }

    // ---- Epilogue: p_i = a_i + b2. sum = sa + 8b; sum(p^2) = sq + 2b*sa + 8b^2 ----
    #pragma unroll
    for (int mt = 0; mt < 2; ++mt)
      #pragma unroll
      for (int r = 0; r < 4; ++r) {
        const int row = l2m + 16 * mt + q * 4 + r;   // batch row (C: row=quad*4+r)
        const int col = l2n + l16;                   // feature
        const size_t o = ((size_t)j * NB + b0 + row) * DS + col;
        const float b  = b2s;
        const float s  = sa[mt][r] + 8.f * b;
        const float s2 = sq[mt][r] + 2.f * b * sa[mt][r] + 8.f * b * b;
        out[o] = s * 0.125f + states[o];
        out[(size_t)NE * NB * DS + o] = (s2 - s * s * 0.125f) * (1.0f / 7.0f);
      }
}

extern "C" void kernel_launch(void* const* d_in, const int* in_sizes, int n_in,
                              void* d_out, int out_size, void* d_ws, size_t ws_size,
                              hipStream_t stream) {
    (void)in_sizes; (void)n_in; (void)d_ws; (void)ws_size; (void)out_size;
    const float* states  = (const float*)d_in[0];
    const float* actions = (const float*)d_in[1];
    const float* W0 = (const float*)d_in[2];
    const float* b0 = (const float*)d_in[3];
    const float* W1 = (const float*)d_in[4];
    const float* b1 = (const float*)d_in[5];
    const float* W2 = (const float*)d_in[6];
    const float* b2 = (const float*)d_in[7];
    float* out = (float*)d_out;
    dim3 grid(NE * (NB / BT));   // 2048 blocks
    ens_mlp_kernel<<<grid, dim3(256), 0, stream>>>(states, actions, W0, b0, W1, b1, W2, b2, out);
}

// Round 7
// 161.720 us; speedup vs baseline: 1.5500x; 1.1390x over previous
//
#include <hip/hip_runtime.h>
#include <hip/hip_bf16.h>

// Ensemble MLP: E=8, B=16384, DS=32, DA=8, H=128, din=40 (padded to 64 for K).
// preds[i,j,b,:] = MLP_j(inp[i,b,:]); out0 = mean_i(preds)+states, out1 = var_i(preds, ddof=1)
//
// R7 = R6 + (a) XOR-swizzled unpadded LDS (kills the 8-way b128 read conflicts
// that padded stride-136 provably has: bank = 4*((l16+q)%8); swizzle spreads
// rows 2-way = free), LDS 44032 -> 40960 (4 blocks/CU if regs allow);
// (b) vectorized staging: dwordx4 loads + cvt_pk + ds_write_b128 (~10 VALU vs
// ~90 scalar). R6 kept: bias0-in-MFMA, weights-as-A for L0/L1 with packed b64
// hidden stores, R4-orientation L2, deferred b2, race-safe prologue.

#define NE 8
#define NB 16384
#define DS 32
#define DA 8
#define HH 128
#define DIN 40
#define BT 64            // batch rows per block
#define SLOPE 0.01f

using bf16x8 = __attribute__((ext_vector_type(8))) short;
using f32x4  = __attribute__((ext_vector_type(4))) float;

__device__ __forceinline__ unsigned short f2bf(float f) {
    unsigned int u = __float_as_uint(f);
    u += 0x7FFFu + ((u >> 16) & 1u);
    return (unsigned short)(u >> 16);
}

__device__ __forceinline__ float lrelu(float x) { return fmaxf(x, SLOPE * x); }

__device__ __forceinline__ unsigned int pack2bf(float a, float b) {
    union { __hip_bfloat162 h; unsigned int u; } cv;
    cv.h = __float22bfloat162_rn(make_float2(a, b));   // a -> low 16, b -> high 16
    return cv.u;
}

// Swizzled element indices (16B blocks of 8 bf16; block' = block ^ row-bits)
__device__ __forceinline__ int sin_idx(int row, int kb) {          // 64 elts/row
    return row * 64 + ((kb ^ (row & 7)) << 3);
}
__device__ __forceinline__ int sh_idx(int row, int kb) {           // 128 elts/row
    return row * 128 + ((kb ^ (row & 15)) << 3);
}

__global__ __launch_bounds__(256, 3)
void ens_mlp_kernel(const float* __restrict__ states,
                    const float* __restrict__ actions,
                    const float* __restrict__ W0g,
                    const float* __restrict__ b0g,
                    const float* __restrict__ W1g,
                    const float* __restrict__ b1g,
                    const float* __restrict__ W2g,
                    const float* __restrict__ b2g,
                    float* __restrict__ out)
{
    __shared__ __align__(16) unsigned short sIn[BT * 64];     //  8 KB
    __shared__ __align__(16) unsigned short sHa[BT * 128];    // 16 KB
    __shared__ __align__(16) unsigned short sHb[BT * 128];    // 16 KB  -> 40960 total

    const int j    = blockIdx.x & 7;          // j fast-varying
    const int bt   = blockIdx.x >> 3;
    const int b0   = bt * BT;
    const int tid  = threadIdx.x;
    const int wave = tid >> 6;
    const int lane = tid & 63;
    const int q    = lane >> 4;
    const int l16  = lane & 15;
    const int fb   = 32 * wave;               // L0/L1: wave owns features fb..fb+31 (A/M dim)
    const int l2m  = 32 * (wave >> 1);        // L2 (R4 orientation): rows l2m..l2m+31
    const int l2n  = 16 * (wave & 1);         //                      cols l2n..l2n+15

    // zero-fill sIn FIRST (swizzle-invariant for zeros); blocks 5..7 stay zero
    // except the ones element written after the barrier.
    {
        uint4 z; z.x = z.y = z.z = z.w = 0u;
        uint4* p = reinterpret_cast<uint4*>(&sIn[tid * 32]);
        p[0] = z; p[1] = z; p[2] = z; p[3] = z;
    }

    const float* W0j = W0g + j * (DIN * HH);
    const float* W1j = W1g + j * (HH * HH);
    const float* W2j = W2g + j * (HH * DS);

    // ---- L0/L1 weight A-fragments: lane holds W[k = ks*32+q*8+t][feat = base+l16]
    bf16x8 w0f[2][2];   // 16 VGPRs; k==40 row carries b0 (bias-via-MFMA)
    bf16x8 w1f[4][2];   // 32 VGPRs
    bf16x8 w2f[4];      // 16 VGPRs (L2 B-frags, R4 orientation)
    float b1r[2][4];
    float b2s;

    #pragma unroll
    for (int ks = 0; ks < 2; ++ks)
      #pragma unroll
      for (int mt = 0; mt < 2; ++mt) {
        const int n = fb + mt * 16 + l16;
        #pragma unroll
        for (int t = 0; t < 8; ++t) {
          const int k = ks * 32 + q * 8 + t;
          const float v = (k < DIN) ? W0j[k * HH + n]
                        : (k == DIN ? b0g[j * HH + n] : 0.f);
          w0f[ks][mt][t] = (short)f2bf(v);
        }
      }
    #pragma unroll
    for (int ks = 0; ks < 4; ++ks)
      #pragma unroll
      for (int mt = 0; mt < 2; ++mt) {
        const int n = fb + mt * 16 + l16;
        #pragma unroll
        for (int t = 0; t < 8; ++t) {
          const int k = ks * 32 + q * 8 + t;
          w1f[ks][mt][t] = (short)f2bf(W1j[k * HH + n]);
        }
      }
    #pragma unroll
    for (int ks = 0; ks < 4; ++ks) {
        const int n = l2n + l16;
        #pragma unroll
        for (int t = 0; t < 8; ++t) {
          const int k = ks * 32 + q * 8 + t;
          w2f[ks][t] = (short)f2bf(W2j[k * DS + n]);
        }
    }
    #pragma unroll
    for (int mt = 0; mt < 2; ++mt)
      #pragma unroll
      for (int r = 0; r < 4; ++r)
        b1r[mt][r] = b1g[j * HH + fb + mt * 16 + q * 4 + r];
    b2s = b2g[j * DS + l2n + l16];

    float sa[2][4], sq[2][4];
    #pragma unroll
    for (int mt = 0; mt < 2; ++mt)
      #pragma unroll
      for (int r = 0; r < 4; ++r) { sa[mt][r] = 0.f; sq[mt][r] = 0.f; }

    const f32x4 z4 = {0.f, 0.f, 0.f, 0.f};

    // staging geometry (constant across i)
    const int srow = tid >> 2;        // states: row 0..63
    const int scb  = tid & 3;         // states: k-block 0..3
    const int soff = srow * DS + scb * 8;          // f32 offset within slice
    unsigned short* const sdst = &sIn[sin_idx(srow, scb)];
    unsigned short* const adst = &sIn[sin_idx(lane, 4)];   // wave 0 only

    __syncthreads();   // zero-fill drained before any sIn rewrites

    // ones element for bias-via-MFMA: (row, col 40) = block 5 elem 0.
    // Disjoint from staged blocks 0..4 -> race-free; persists across i.
    if (tid < BT) sIn[sin_idx(tid, 5)] = 0x3F80;  // bf16 1.0

    // ---- stage inp[0] (vectorized) ----
    {
        const float4* sp = reinterpret_cast<const float4*>(states + (size_t)b0 * DS + soff);
        const float4 f0 = sp[0], f1 = sp[1];
        uint4 pk;
        pk.x = pack2bf(f0.x, f0.y); pk.y = pack2bf(f0.z, f0.w);
        pk.z = pack2bf(f1.x, f1.y); pk.w = pack2bf(f1.z, f1.w);
        *reinterpret_cast<uint4*>(sdst) = pk;
        if (tid < BT) {
            const float4* ap = reinterpret_cast<const float4*>(actions + ((size_t)b0 + lane) * DA);
            const float4 a0 = ap[0], a1 = ap[1];
            uint4 apk;
            apk.x = pack2bf(a0.x, a0.y); apk.y = pack2bf(a0.z, a0.w);
            apk.z = pack2bf(a1.x, a1.y); apk.w = pack2bf(a1.z, a1.w);
            *reinterpret_cast<uint4*>(adst) = apk;
        }
    }
    __syncthreads();

    for (int i = 0; i < NE; ++i) {
        // ---- Layer 0: h0 = lrelu(inp @ W0 [+b0 via k=40]); A=W0(m=feat), B=inp(n=batch)
        #pragma unroll
        for (int nh = 0; nh < 2; ++nh) {          // batch halves
            f32x4 acc[2][2];
            #pragma unroll
            for (int mt = 0; mt < 2; ++mt)
              #pragma unroll
              for (int nt = 0; nt < 2; ++nt) acc[mt][nt] = z4;
            #pragma unroll
            for (int ks = 0; ks < 2; ++ks) {
                bf16x8 bf[2];
                #pragma unroll
                for (int nt = 0; nt < 2; ++nt) {
                    const int row = nh * 32 + nt * 16 + l16;   // B: n = lane&15
                    bf[nt] = *(const bf16x8*)(&sIn[sin_idx(row, ks * 4 + q)]);
                }
                #pragma unroll
                for (int mt = 0; mt < 2; ++mt)
                  #pragma unroll
                  for (int nt = 0; nt < 2; ++nt)
                    acc[mt][nt] = __builtin_amdgcn_mfma_f32_16x16x32_bf16(
                        w0f[ks][mt], bf[nt], acc[mt][nt], 0, 0, 0);
            }
            // lane holds 4 consecutive features (q*4+r) of batch row nt*16+l16
            #pragma unroll
            for (int mt = 0; mt < 2; ++mt)
              #pragma unroll
              for (int nt = 0; nt < 2; ++nt) {
                const int row = nh * 32 + nt * 16 + l16;
                const int blk = (fb >> 3) + mt * 2 + (q >> 1);
                const int idx = sh_idx(row, blk) + (q & 1) * 4;
                const float v0 = lrelu(acc[mt][nt][0]);   // b0 already in acc
                const float v1 = lrelu(acc[mt][nt][1]);
                const float v2 = lrelu(acc[mt][nt][2]);
                const float v3 = lrelu(acc[mt][nt][3]);
                uint2 pk; pk.x = pack2bf(v0, v1); pk.y = pack2bf(v2, v3);
                *reinterpret_cast<uint2*>(&sHa[idx]) = pk;
              }
        }
        __syncthreads();   // B2: h0 ready; sIn reads drained (safe to restage)

        // ---- stage inp[i+1] (overlaps L1; writes blocks 0..4 only) ----
        if (i < NE - 1) {
            const float4* sp = reinterpret_cast<const float4*>(
                states + ((size_t)(i + 1) * NB + b0) * DS + soff);
            const float4 f0 = sp[0], f1 = sp[1];
            uint4 pk;
            pk.x = pack2bf(f0.x, f0.y); pk.y = pack2bf(f0.z, f0.w);
            pk.z = pack2bf(f1.x, f1.y); pk.w = pack2bf(f1.z, f1.w);
            *reinterpret_cast<uint4*>(sdst) = pk;
            if (tid < BT) {
                const float4* ap = reinterpret_cast<const float4*>(
                    actions + ((size_t)(i + 1) * NB + b0 + lane) * DA);
                const float4 a0 = ap[0], a1 = ap[1];
                uint4 apk;
                apk.x = pack2bf(a0.x, a0.y); apk.y = pack2bf(a0.z, a0.w);
                apk.z = pack2bf(a1.x, a1.y); apk.w = pack2bf(a1.z, a1.w);
                *reinterpret_cast<uint4*>(adst) = apk;
            }
        }

        // ---- Layer 1: h1 = lrelu(h0 @ W1 + b1), K=128; reads sHa, writes sHb ----
        #pragma unroll
        for (int nh = 0; nh < 2; ++nh) {
            f32x4 acc[2][2];
            #pragma unroll
            for (int mt = 0; mt < 2; ++mt)
              #pragma unroll
              for (int nt = 0; nt < 2; ++nt) acc[mt][nt] = z4;
            #pragma unroll
            for (int ks = 0; ks < 4; ++ks) {
                bf16x8 bf[2];
                #pragma unroll
                for (int nt = 0; nt < 2; ++nt) {
                    const int row = nh * 32 + nt * 16 + l16;
                    bf[nt] = *(const bf16x8*)(&sHa[sh_idx(row, ks * 4 + q)]);
                }
                #pragma unroll
                for (int mt = 0; mt < 2; ++mt)
                  #pragma unroll
                  for (int nt = 0; nt < 2; ++nt)
                    acc[mt][nt] = __builtin_amdgcn_mfma_f32_16x16x32_bf16(
                        w1f[ks][mt], bf[nt], acc[mt][nt], 0, 0, 0);
            }
            #pragma unroll
            for (int mt = 0; mt < 2; ++mt)
              #pragma unroll
              for (int nt = 0; nt < 2; ++nt) {
                const int row = nh * 32 + nt * 16 + l16;
                const int blk = (fb >> 3) + mt * 2 + (q >> 1);
                const int idx = sh_idx(row, blk) + (q & 1) * 4;
                const float v0 = lrelu(acc[mt][nt][0] + b1r[mt][0]);
                const float v1 = lrelu(acc[mt][nt][1] + b1r[mt][1]);
                const float v2 = lrelu(acc[mt][nt][2] + b1r[mt][2]);
                const float v3 = lrelu(acc[mt][nt][3] + b1r[mt][3]);
                uint2 pk; pk.x = pack2bf(v0, v1); pk.y = pack2bf(v2, v3);
                *reinterpret_cast<uint2*>(&sHb[idx]) = pk;
              }
        }
        __syncthreads();   // B3: h1 + sIn(i+1) ready

        // ---- Layer 2 (R4 orientation): A=h1 (m=batch), B=W2 (n=feature) ----
        {
            f32x4 acc2[2];
            acc2[0] = z4; acc2[1] = z4;
            #pragma unroll
            for (int ks = 0; ks < 4; ++ks) {
                #pragma unroll
                for (int mt = 0; mt < 2; ++mt) {
                    const int row = l2m + 16 * mt + l16;
                    const bf16x8 a2 = *(const bf16x8*)(&sHb[sh_idx(row, ks * 4 + q)]);
                    acc2[mt] = __builtin_amdgcn_mfma_f32_16x16x32_bf16(
                        a2, w2f[ks], acc2[mt], 0, 0, 0);
                }
            }
            #pragma unroll
            for (int mt = 0; mt < 2; ++mt)
              #pragma unroll
              for (int r = 0; r < 4; ++r) {
                const float a = acc2[mt][r];      // b2 deferred
                sa[mt][r] += a;
                sq[mt][r] = fmaf(a, a, sq[mt][r]);
              }
        }
    }

    // ---- Epilogue: p_i = a_i + b2. sum = sa + 8b; sum(p^2) = sq + 2b*sa + 8b^2 ----
    #pragma unroll
    for (int mt = 0; mt < 2; ++mt)
      #pragma unroll
      for (int r = 0; r < 4; ++r) {
        const int row = l2m + 16 * mt + q * 4 + r;   // batch row (C: row=quad*4+r)
        const int col = l2n + l16;                   // feature
        const size_t o = ((size_t)j * NB + b0 + row) * DS + col;
        const float b  = b2s;
        const float s  = sa[mt][r] + 8.f * b;
        const float s2 = sq[mt][r] + 2.f * b * sa[mt][r] + 8.f * b * b;
        out[o] = s * 0.125f + states[o];
        out[(size_t)NE * NB * DS + o] = (s2 - s * s * 0.125f) * (1.0f / 7.0f);
      }
}

extern "C" void kernel_launch(void* const* d_in, const int* in_sizes, int n_in,
                              void* d_out, int out_size, void* d_ws, size_t ws_size,
                              hipStream_t stream) {
    (void)in_sizes; (void)n_in; (void)d_ws; (void)ws_size; (void)out_size;
    const float* states  = (const float*)d_in[0];
    const float* actions = (const float*)d_in[1];
    const float* W0 = (const float*)d_in[2];
    const float* b0 = (const float*)d_in[3];
    const float* W1 = (const float*)d_in[4];
    const float* b1 = (const float*)d_in[5];
    const float* W2 = (const float*)d_in[6];
    const float* b2 = (const float*)d_in[7];
    float* out = (float*)d_out;
    dim3 grid(NE * (NB / BT));   // 2048 blocks
    ens_mlp_kernel<<<grid, dim3(256), 0, stream>>>(states, actions, W0, b0, W1, b1, W2, b2, out);
}

// Round 8
// 153.949 us; speedup vs baseline: 1.6282x; 1.0505x over previous
//
#include <hip/hip_runtime.h>
#include <hip/hip_bf16.h>

// Ensemble MLP: E=8, B=16384, DS=32, DA=8, H=128, din=40 (padded to 64 for K).
// preds[i,j,b,:] = MLP_j(inp[i,b,:]); out0 = mean_i(preds)+states, out1 = var_i(preds, ddof=1)
//
// R8 = R7 + (a) persistent blocks: grid = 768 (= 3/CU x 256, one generation);
// each block keeps its weight fragments and loops bt = slot, slot+96, ... .
// Prologues 2048 -> 768, no generation churn (R7: VALU 52% incl. 2048 weight
// prologues of ~128 scalar loads + ~600 cvt VALU each).
// (b) bias-as-acc-init: L0/L1 accumulators initialize to b0/b1 instead of 0
// (deletes L1 bias adds + the ones-column/k=40 machinery of R6/R7).
// Kept from R7: XOR-swizzled unpadded LDS (40960 B), vectorized dwordx4+cvt_pk
// staging, weights-as-A for L0/L1 with packed b64 hidden stores, R4-orientation
// L2, deferred b2 algebra, race-safe prologue ordering.

#define NE 8
#define NB 16384
#define DS 32
#define DA 8
#define HH 128
#define DIN 40
#define BT 64            // batch rows per block-tile
#define NSLOT 96         // bt slots (grid = 8*NSLOT = 768)
#define SLOPE 0.01f

using bf16x8 = __attribute__((ext_vector_type(8))) short;
using f32x4  = __attribute__((ext_vector_type(4))) float;

__device__ __forceinline__ unsigned short f2bf(float f) {
    unsigned int u = __float_as_uint(f);
    u += 0x7FFFu + ((u >> 16) & 1u);
    return (unsigned short)(u >> 16);
}

__device__ __forceinline__ float lrelu(float x) { return fmaxf(x, SLOPE * x); }

__device__ __forceinline__ unsigned int pack2bf(float a, float b) {
    union { __hip_bfloat162 h; unsigned int u; } cv;
    cv.h = __float22bfloat162_rn(make_float2(a, b));   // a -> low 16, b -> high 16
    return cv.u;
}

// Swizzled element indices (16B blocks of 8 bf16; block' = block ^ row-bits)
__device__ __forceinline__ int sin_idx(int row, int kb) {          // 64 elts/row
    return row * 64 + ((kb ^ (row & 7)) << 3);
}
__device__ __forceinline__ int sh_idx(int row, int kb) {           // 128 elts/row
    return row * 128 + ((kb ^ (row & 15)) << 3);
}

__global__ __launch_bounds__(256, 3)
void ens_mlp_kernel(const float* __restrict__ states,
                    const float* __restrict__ actions,
                    const float* __restrict__ W0g,
                    const float* __restrict__ b0g,
                    const float* __restrict__ W1g,
                    const float* __restrict__ b1g,
                    const float* __restrict__ W2g,
                    const float* __restrict__ b2g,
                    float* __restrict__ out)
{
    __shared__ __align__(16) unsigned short sIn[BT * 64];     //  8 KB
    __shared__ __align__(16) unsigned short sHa[BT * 128];    // 16 KB
    __shared__ __align__(16) unsigned short sHb[BT * 128];    // 16 KB  -> 40960 total

    const int j    = blockIdx.x & 7;          // j fast-varying
    const int slot = blockIdx.x >> 3;         // 0..95
    const int tid  = threadIdx.x;
    const int wave = tid >> 6;
    const int lane = tid & 63;
    const int q    = lane >> 4;
    const int l16  = lane & 15;
    const int fb   = 32 * wave;               // L0/L1: wave owns features fb..fb+31 (A/M dim)
    const int l2m  = 32 * (wave >> 1);        // L2 (R4 orientation): rows l2m..l2m+31
    const int l2n  = 16 * (wave & 1);         //                      cols l2n..l2n+15

    // zero-fill sIn once (swizzle-invariant); blocks 5..7 stay zero forever
    // (staging only writes blocks 0..4) = K padding cols 40..63.
    {
        uint4 z; z.x = z.y = z.z = z.w = 0u;
        uint4* p = reinterpret_cast<uint4*>(&sIn[tid * 32]);
        p[0] = z; p[1] = z; p[2] = z; p[3] = z;
    }

    const float* W0j = W0g + j * (DIN * HH);
    const float* W1j = W1g + j * (HH * HH);
    const float* W2j = W2g + j * (HH * DS);

    // ---- L0/L1 weight A-fragments: lane holds W[k = ks*32+q*8+t][feat = base+l16]
    bf16x8 w0f[2][2];   // 16 VGPRs (k >= 40 rows zero)
    bf16x8 w1f[4][2];   // 32 VGPRs
    bf16x8 w2f[4];      // 16 VGPRs (L2 B-frags, R4 orientation)
    f32x4 b0v[2], b1v[2];   // acc-init biases, C-layout (lane owns feats q*4+r)
    float b2s;

    #pragma unroll
    for (int ks = 0; ks < 2; ++ks)
      #pragma unroll
      for (int mt = 0; mt < 2; ++mt) {
        const int n = fb + mt * 16 + l16;
        #pragma unroll
        for (int t = 0; t < 8; ++t) {
          const int k = ks * 32 + q * 8 + t;
          w0f[ks][mt][t] = (short)((k < DIN) ? f2bf(W0j[k * HH + n]) : 0);
        }
      }
    #pragma unroll
    for (int ks = 0; ks < 4; ++ks)
      #pragma unroll
      for (int mt = 0; mt < 2; ++mt) {
        const int n = fb + mt * 16 + l16;
        #pragma unroll
        for (int t = 0; t < 8; ++t) {
          const int k = ks * 32 + q * 8 + t;
          w1f[ks][mt][t] = (short)f2bf(W1j[k * HH + n]);
        }
      }
    #pragma unroll
    for (int ks = 0; ks < 4; ++ks) {
        const int n = l2n + l16;
        #pragma unroll
        for (int t = 0; t < 8; ++t) {
          const int k = ks * 32 + q * 8 + t;
          w2f[ks][t] = (short)f2bf(W2j[k * DS + n]);
        }
    }
    #pragma unroll
    for (int mt = 0; mt < 2; ++mt)
      #pragma unroll
      for (int r = 0; r < 4; ++r) {
        b0v[mt][r] = b0g[j * HH + fb + mt * 16 + q * 4 + r];
        b1v[mt][r] = b1g[j * HH + fb + mt * 16 + q * 4 + r];
      }
    b2s = b2g[j * DS + l2n + l16];

    const f32x4 z4 = {0.f, 0.f, 0.f, 0.f};

    // staging geometry (constant across i and bt)
    const int srow = tid >> 2;        // states: row 0..63
    const int scb  = tid & 3;         // states: k-block 0..3
    const int soff = srow * DS + scb * 8;          // f32 offset within slice
    unsigned short* const sdst = &sIn[sin_idx(srow, scb)];
    unsigned short* const adst = &sIn[sin_idx(lane, 4)];   // wave 0 only

    for (int bt = slot; bt < NB / BT; bt += NSLOT) {
        const int b0 = bt * BT;

        // ---- stage inp[0] (vectorized). Safe: last sIn reads of the previous
        // bt (L0 i=7) completed before its B2; epilogue touches no LDS.
        // First bt: zero-fill above is pre-barrier for waves... all waves wrote
        // their own quarter; barrier below publishes everything before L0 reads.
        {
            const float4* sp = reinterpret_cast<const float4*>(
                states + (size_t)b0 * DS + soff);
            const float4 f0 = sp[0], f1 = sp[1];
            uint4 pk;
            pk.x = pack2bf(f0.x, f0.y); pk.y = pack2bf(f0.z, f0.w);
            pk.z = pack2bf(f1.x, f1.y); pk.w = pack2bf(f1.z, f1.w);
            *reinterpret_cast<uint4*>(sdst) = pk;
            if (tid < BT) {
                const float4* ap = reinterpret_cast<const float4*>(
                    actions + ((size_t)b0 + lane) * DA);
                const float4 a0 = ap[0], a1 = ap[1];
                uint4 apk;
                apk.x = pack2bf(a0.x, a0.y); apk.y = pack2bf(a0.z, a0.w);
                apk.z = pack2bf(a1.x, a1.y); apk.w = pack2bf(a1.z, a1.w);
                *reinterpret_cast<uint4*>(adst) = apk;
            }
        }
        __syncthreads();

        float sa[2][4], sq[2][4];
        #pragma unroll
        for (int mt = 0; mt < 2; ++mt)
          #pragma unroll
          for (int r = 0; r < 4; ++r) { sa[mt][r] = 0.f; sq[mt][r] = 0.f; }

        for (int i = 0; i < NE; ++i) {
            // ---- Layer 0: h0 = lrelu(W0^T inp + b0); acc init = b0 ----
            #pragma unroll
            for (int nh = 0; nh < 2; ++nh) {          // batch halves
                f32x4 acc[2][2];
                #pragma unroll
                for (int mt = 0; mt < 2; ++mt)
                  #pragma unroll
                  for (int nt = 0; nt < 2; ++nt) acc[mt][nt] = b0v[mt];
                #pragma unroll
                for (int ks = 0; ks < 2; ++ks) {
                    bf16x8 bf[2];
                    #pragma unroll
                    for (int nt = 0; nt < 2; ++nt) {
                        const int row = nh * 32 + nt * 16 + l16;   // B: n = lane&15
                        bf[nt] = *(const bf16x8*)(&sIn[sin_idx(row, ks * 4 + q)]);
                    }
                    #pragma unroll
                    for (int mt = 0; mt < 2; ++mt)
                      #pragma unroll
                      for (int nt = 0; nt < 2; ++nt)
                        acc[mt][nt] = __builtin_amdgcn_mfma_f32_16x16x32_bf16(
                            w0f[ks][mt], bf[nt], acc[mt][nt], 0, 0, 0);
                }
                // lane holds 4 consecutive features (q*4+r) of batch row nt*16+l16
                #pragma unroll
                for (int mt = 0; mt < 2; ++mt)
                  #pragma unroll
                  for (int nt = 0; nt < 2; ++nt) {
                    const int row = nh * 32 + nt * 16 + l16;
                    const int blk = (fb >> 3) + mt * 2 + (q >> 1);
                    const int idx = sh_idx(row, blk) + (q & 1) * 4;
                    const float v0 = lrelu(acc[mt][nt][0]);
                    const float v1 = lrelu(acc[mt][nt][1]);
                    const float v2 = lrelu(acc[mt][nt][2]);
                    const float v3 = lrelu(acc[mt][nt][3]);
                    uint2 pk; pk.x = pack2bf(v0, v1); pk.y = pack2bf(v2, v3);
                    *reinterpret_cast<uint2*>(&sHa[idx]) = pk;
                  }
            }
            __syncthreads();   // B2: h0 ready; sIn reads drained

            // ---- stage inp[i+1] (overlaps L1; writes blocks 0..4 only) ----
            if (i < NE - 1) {
                const float4* sp = reinterpret_cast<const float4*>(
                    states + ((size_t)(i + 1) * NB + b0) * DS + soff);
                const float4 f0 = sp[0], f1 = sp[1];
                uint4 pk;
                pk.x = pack2bf(f0.x, f0.y); pk.y = pack2bf(f0.z, f0.w);
                pk.z = pack2bf(f1.x, f1.y); pk.w = pack2bf(f1.z, f1.w);
                *reinterpret_cast<uint4*>(sdst) = pk;
                if (tid < BT) {
                    const float4* ap = reinterpret_cast<const float4*>(
                        actions + ((size_t)(i + 1) * NB + b0 + lane) * DA);
                    const float4 a0 = ap[0], a1 = ap[1];
                    uint4 apk;
                    apk.x = pack2bf(a0.x, a0.y); apk.y = pack2bf(a0.z, a0.w);
                    apk.z = pack2bf(a1.x, a1.y); apk.w = pack2bf(a1.z, a1.w);
                    *reinterpret_cast<uint4*>(adst) = apk;
                }
            }

            // ---- Layer 1: h1 = lrelu(W1^T h0 + b1); acc init = b1 ----
            #pragma unroll
            for (int nh = 0; nh < 2; ++nh) {
                f32x4 acc[2][2];
                #pragma unroll
                for (int mt = 0; mt < 2; ++mt)
                  #pragma unroll
                  for (int nt = 0; nt < 2; ++nt) acc[mt][nt] = b1v[mt];
                #pragma unroll
                for (int ks = 0; ks < 4; ++ks) {
                    bf16x8 bf[2];
                    #pragma unroll
                    for (int nt = 0; nt < 2; ++nt) {
                        const int row = nh * 32 + nt * 16 + l16;
                        bf[nt] = *(const bf16x8*)(&sHa[sh_idx(row, ks * 4 + q)]);
                    }
                    #pragma unroll
                    for (int mt = 0; mt < 2; ++mt)
                      #pragma unroll
                      for (int nt = 0; nt < 2; ++nt)
                        acc[mt][nt] = __builtin_amdgcn_mfma_f32_16x16x32_bf16(
                            w1f[ks][mt], bf[nt], acc[mt][nt], 0, 0, 0);
                }
                #pragma unroll
                for (int mt = 0; mt < 2; ++mt)
                  #pragma unroll
                  for (int nt = 0; nt < 2; ++nt) {
                    const int row = nh * 32 + nt * 16 + l16;
                    const int blk = (fb >> 3) + mt * 2 + (q >> 1);
                    const int idx = sh_idx(row, blk) + (q & 1) * 4;
                    const float v0 = lrelu(acc[mt][nt][0]);
                    const float v1 = lrelu(acc[mt][nt][1]);
                    const float v2 = lrelu(acc[mt][nt][2]);
                    const float v3 = lrelu(acc[mt][nt][3]);
                    uint2 pk; pk.x = pack2bf(v0, v1); pk.y = pack2bf(v2, v3);
                    *reinterpret_cast<uint2*>(&sHb[idx]) = pk;
                  }
            }
            __syncthreads();   // B3: h1 + sIn(i+1) ready

            // ---- Layer 2 (R4 orientation): A=h1 (m=batch), B=W2 (n=feature) ----
            {
                f32x4 acc2[2];
                acc2[0] = z4; acc2[1] = z4;
                #pragma unroll
                for (int ks = 0; ks < 4; ++ks) {
                    #pragma unroll
                    for (int mt = 0; mt < 2; ++mt) {
                        const int row = l2m + 16 * mt + l16;
                        const bf16x8 a2 = *(const bf16x8*)(&sHb[sh_idx(row, ks * 4 + q)]);
                        acc2[mt] = __builtin_amdgcn_mfma_f32_16x16x32_bf16(
                            a2, w2f[ks], acc2[mt], 0, 0, 0);
                    }
                }
                #pragma unroll
                for (int mt = 0; mt < 2; ++mt)
                  #pragma unroll
                  for (int r = 0; r < 4; ++r) {
                    const float a = acc2[mt][r];      // b2 deferred
                    sa[mt][r] += a;
                    sq[mt][r] = fmaf(a, a, sq[mt][r]);
                  }
            }
        }

        // ---- Epilogue for this bt: sum = sa + 8b; sum(p^2) = sq + 2b*sa + 8b^2
        #pragma unroll
        for (int mt = 0; mt < 2; ++mt)
          #pragma unroll
          for (int r = 0; r < 4; ++r) {
            const int row = l2m + 16 * mt + q * 4 + r;   // batch row (C: row=quad*4+r)
            const int col = l2n + l16;                   // feature
            const size_t o = ((size_t)j * NB + b0 + row) * DS + col;
            const float b  = b2s;
            const float s  = sa[mt][r] + 8.f * b;
            const float s2 = sq[mt][r] + 2.f * b * sa[mt][r] + 8.f * b * b;
            out[o] = s * 0.125f + states[o];
            out[(size_t)NE * NB * DS + o] = (s2 - s * s * 0.125f) * (1.0f / 7.0f);
          }
    }
}

extern "C" void kernel_launch(void* const* d_in, const int* in_sizes, int n_in,
                              void* d_out, int out_size, void* d_ws, size_t ws_size,
                              hipStream_t stream) {
    (void)in_sizes; (void)n_in; (void)d_ws; (void)ws_size; (void)out_size;
    const float* states  = (const float*)d_in[0];
    const float* actions = (const float*)d_in[1];
    const float* W0 = (const float*)d_in[2];
    const float* b0 = (const float*)d_in[3];
    const float* W1 = (const float*)d_in[4];
    const float* b1 = (const float*)d_in[5];
    const float* W2 = (const float*)d_in[6];
    const float* b2 = (const float*)d_in[7];
    float* out = (float*)d_out;
    dim3 grid(8 * NSLOT);   // 768 persistent blocks = 3/CU, one generation
    ens_mlp_kernel<<<grid, dim3(256), 0, stream>>>(states, actions, W0, b0, W1, b1, W2, b2, out);
}